// Round 16
// baseline (479.427 us; speedup 1.0000x reference)
//
#include <hip/hip_runtime.h>
#include <stdint.h>

// Problem constants
#define B_    4
#define T_    2048
#define C_    2048
#define H_    16
#define HKV_  8
#define D_    128
#define HD_   2048      // H_*D_
#define KVD_  1024      // HKV_*D_
#define NQKV_ 4096      // HD_+2*KVD_
#define BT_   8192      // B_*T_

typedef __bf16 bf16x8 __attribute__((ext_vector_type(8)));
typedef float  f32x4  __attribute__((ext_vector_type(4)));
typedef unsigned short u16;
typedef unsigned int   u32;

__device__ __forceinline__ u16 f2b(float f){
  union { float f; u32 u; } v; v.f = f;
  u32 r = v.u + 0x7FFFu + ((v.u >> 16) & 1u);   // RNE
  return (u16)(r >> 16);
}
__device__ __forceinline__ float b2f(u16 h){
  union { u32 u; float f; } v; v.u = ((u32)h) << 16;
  return v.f;
}

#define GLOAD16(src, dst) __builtin_amdgcn_global_load_lds( \
    (const __attribute__((address_space(1))) u32*)(src), \
    (__attribute__((address_space(3))) u32*)(dst), 16, 0, 0)

#define MFMA16(a,b,c) __builtin_amdgcn_mfma_f32_16x16x32_bf16((a), (b), (c), 0, 0, 0)

// ---------------------------------------------------------------------------
// merged: fp32->bf16 convert (x) + bias concat + per-batch lens
__global__ __launch_bounds__(256) void k_misc(const float* __restrict__ x, u16* __restrict__ xb,
                                              const float* __restrict__ bq, const float* __restrict__ bk,
                                              const float* __restrict__ bv, float* __restrict__ bias,
                                              const int* __restrict__ mask, int* __restrict__ lens){
  int bid = blockIdx.x;
  if (bid < 16384){
    size_t i = ((size_t)bid * 256 + threadIdx.x) * 4;
    float4 v = *(const float4*)(x + i);
    u32 w0 = (u32)f2b(v.x) | ((u32)f2b(v.y) << 16);
    u32 w1 = (u32)f2b(v.z) | ((u32)f2b(v.w) << 16);
    uint2 pk; pk.x = w0; pk.y = w1;
    *(uint2*)(xb + i) = pk;
  } else if (bid < 16400){
    int i = (bid - 16384) * 256 + threadIdx.x;
    if (i < NQKV_)
      bias[i] = (i < HD_) ? bq[i] : (i < HD_ + KVD_ ? bk[i - HD_] : bv[i - HD_ - KVD_]);
  } else {
    int b = bid - 16400;
    int s = 0;
    for (int t = threadIdx.x; t < T_; t += 256) s += mask[b * T_ + t];
    #pragma unroll
    for (int d = 1; d < 64; d <<= 1) s += __shfl_xor(s, d);
    __shared__ int acc[4];
    if ((threadIdx.x & 63) == 0) acc[threadIdx.x >> 6] = s;
    __syncthreads();
    if (threadIdx.x == 0) lens[b] = acc[0] + acc[1] + acc[2] + acc[3];
  }
}

// transpose + convert all four weights in one launch.
__global__ __launch_bounds__(256) void k_wtrans(const float* __restrict__ Wq, const float* __restrict__ Wk,
                                                const float* __restrict__ Wv, const float* __restrict__ Wo,
                                                u16* __restrict__ WQKVT, u16* __restrict__ WOT){
  int z = blockIdx.z;
  const float* src; u16* dst; int N;
  if (z == 0){ src = Wq; dst = WQKVT;                          N = 2048; }
  else if (z == 1){ src = Wo; dst = WOT;                       N = 2048; }
  else if (z == 2){ src = Wk; dst = WQKVT + (size_t)HD_ * C_;  N = 1024; }
  else { src = Wv; dst = WQKVT + (size_t)(HD_ + KVD_) * C_;    N = 1024; }
  if (blockIdx.x * 64 >= N) return;
  const int K = 2048;
  __shared__ __attribute__((aligned(16))) u16 tile[64][68];
  int n0 = blockIdx.x * 64, k0 = blockIdx.y * 64;
  int r = threadIdx.x >> 4, c4 = (threadIdx.x & 15) * 4;
  #pragma unroll
  for (int rr = 0; rr < 4; ++rr){
    int kl = r + rr * 16;
    float4 v = *(const float4*)(src + (size_t)(k0 + kl) * N + n0 + c4);
    tile[kl][c4+0] = f2b(v.x); tile[kl][c4+1] = f2b(v.y);
    tile[kl][c4+2] = f2b(v.z); tile[kl][c4+3] = f2b(v.w);
  }
  __syncthreads();
  #pragma unroll
  for (int rr = 0; rr < 4; ++rr){
    int nl = r + rr * 16;
    u32 w0 = (u32)tile[c4+0][nl] | ((u32)tile[c4+1][nl] << 16);
    u32 w1 = (u32)tile[c4+2][nl] | ((u32)tile[c4+3][nl] << 16);
    uint2 pk; pk.x = w0; pk.y = w1;
    *(uint2*)(dst + (size_t)(n0 + nl) * K + k0 + c4) = pk;
  }
}

// ---------------------------------------------------------------------------
// bf16 GEMM, R16: 2-phase template at 128x256 tile, BK=32, 8 waves (2M x 4N),
// 48KB dbuf LDS + VGPR<=128 (__launch_bounds__(512,4)) -> 2 blocks/CU; block
// A's MFMA hides block B's barrier/vmcnt drain (m114 cross-block overlap the
// 256^2/1-block shape lacked). 3 gload_lds/thread/tile, counted vmcnt(3),
// ONE barrier each side. Swizzle: granule g -> g^((row>>1)&3) within 32-col
// rows (derivation: 8 distinct 4-bank starts x 2 lanes = conflict-free b128).
template<bool OUTF32>
__global__ __launch_bounds__(512, 4) void k_gemm(const u16* __restrict__ A, const u16* __restrict__ BT,
                                                 const float* __restrict__ bias, void* __restrict__ Cout,
                                                 int M, int N, int K, int nbx){
  __shared__ __attribute__((aligned(16))) u16 As[2][128 * 32];   // 16 KB
  __shared__ __attribute__((aligned(16))) u16 Bs[2][256 * 32];   // 32 KB
  int nwg = gridDim.x;
  int fid = blockIdx.x;
  int gs = (fid & 7) * (nwg >> 3) + (fid >> 3);   // XCD-chunked decode
  int bx = gs % nbx, by = gs / nbx;
  int m0 = by * 128, n0 = bx * 256;
  int tid = threadIdx.x;
  int lane = tid & 63, w = tid >> 6;              // 8 waves
  int wm = w >> 2, wn = w & 3;                    // 2 x 4 wave grid
  int g = lane >> 4, lo = lane & 15;
  f32x4 acc[4][4] = {};

  // A: 128 rows x 4 granules = 512 slots = 1 load/thread.
  // B: 256 rows x 4 granules = 1024 slots = 2 loads/thread.
  // LDS dest is linear (slot*16B); source granule pre-swizzled by (row>>1)&3.
  auto STAGE_TILE = [&](int k0, int bufi){
    {
      int row = tid >> 2, gr = tid & 3;
      GLOAD16(A + (size_t)(m0 + row) * K + k0 + ((gr ^ ((row >> 1) & 3)) << 3),
              &As[bufi][(tid & 448) * 8]);
    }
    #pragma unroll
    for (int i = 0; i < 2; ++i){
      int gI = i * 512 + tid;
      int row = gI >> 2, gr = gI & 3;
      GLOAD16(BT + (size_t)(n0 + row) * K + k0 + ((gr ^ ((row >> 1) & 3)) << 3),
              &Bs[bufi][(i * 512 + (tid & 448)) * 8]);
    }
  };

  int nk = K >> 5;                       // BK = 32
  STAGE_TILE(0, 0);
  for (int t = 0; t < nk; ++t){
    int cur = t & 1, nxt = cur ^ 1;
    bool pf = (t + 1 < nk);
    if (pf){
      STAGE_TILE((t + 1) * 32, nxt);
      asm volatile("s_waitcnt vmcnt(3)" ::: "memory");   // tile t's 3 landed
    } else {
      asm volatile("s_waitcnt vmcnt(0)" ::: "memory");
    }
    __builtin_amdgcn_s_barrier();
    __builtin_amdgcn_sched_barrier(0);
    bf16x8 bfr[4], af[4];
    #pragma unroll
    for (int nr = 0; nr < 4; ++nr){
      int brow = wn * 64 + nr * 16 + lo;
      bfr[nr] = *(const bf16x8*)&Bs[cur][brow * 32 + ((g ^ ((brow >> 1) & 3)) << 3)];
    }
    #pragma unroll
    for (int mr = 0; mr < 4; ++mr){
      int arow = wm * 64 + mr * 16 + lo;
      af[mr] = *(const bf16x8*)&As[cur][arow * 32 + ((g ^ ((arow >> 1) & 3)) << 3)];
    }
    __builtin_amdgcn_s_setprio(1);
    #pragma unroll
    for (int mr = 0; mr < 4; ++mr)
      #pragma unroll
      for (int nr = 0; nr < 4; ++nr)
        acc[mr][nr] = MFMA16(af[mr], bfr[nr], acc[mr][nr]);
    __builtin_amdgcn_s_setprio(0);
    __builtin_amdgcn_s_barrier();
  }
  #pragma unroll
  for (int mr = 0; mr < 4; ++mr){
    #pragma unroll
    for (int nr = 0; nr < 4; ++nr){
      #pragma unroll
      for (int r = 0; r < 4; ++r){
        int row = m0 + wm * 64 + mr * 16 + g * 4 + r;
        int col = n0 + wn * 64 + nr * 16 + lo;
        float v = acc[mr][nr][r] + (bias ? bias[col] : 0.0f);
        if (OUTF32) ((float*)Cout)[(size_t)row * N + col] = v;
        else        ((u16*)Cout)[(size_t)row * N + col] = f2b(v);
      }
    }
  }
}

// ---------------------------------------------------------------------------
// merged post-QKV pass: blocks 0..8191 = RMSNorm+mRoPE (per token);
// blocks 8192..10239 = masked V transpose. Disjoint outputs, both read QKV.
__global__ __launch_bounds__(256) void k_post(const u16* __restrict__ qkv,
    const float* __restrict__ cosp, const float* __restrict__ sinp,
    const int* __restrict__ mask, const float* __restrict__ gq, const float* __restrict__ gk,
    u16* __restrict__ qrot, u16* __restrict__ krot, u16* __restrict__ vt){
  int bid = blockIdx.x;
  if (bid < BT_){
    const float QS = 0.08838834764831845f * 1.4426950408889634f;  // scale * log2e
    int tok = bid;
    int b = tok >> 11, t = tok & (T_ - 1);
    int lane = threadIdx.x & 63, w = threadIdx.x >> 6;
    int dl = (lane & 31) * 2;                 // index into the 64-entry half table
    int a0 = dl < 24 ? 0 : (dl < 44 ? 1 : 2);
    int a1 = (dl + 1) < 24 ? 0 : ((dl + 1) < 44 ? 1 : 2);
    size_t cb = ((size_t)b * T_ + t) * 64;
    const size_t AX = (size_t)B_ * T_ * 64;
    float ce0 = cosp[(size_t)a0 * AX + cb + dl],     se0 = sinp[(size_t)a0 * AX + cb + dl];
    float ce1 = cosp[(size_t)a1 * AX + cb + dl + 1], se1 = sinp[(size_t)a1 * AX + cb + dl + 1];
    float sgn = (lane < 32) ? -1.f : 1.f;
    float mk = (float)mask[b * T_ + t];
    const u16* base = qkv + (size_t)tok * NQKV_;
    for (int head = w; head < H_ + HKV_; head += 4){
      bool isq = head < H_;
      int off = isq ? head * D_ : HD_ + (head - H_) * D_;
      u32 pr = *(const u32*)(base + off + lane * 2);
      float x0 = b2f((u16)(pr & 0xFFFF)), x1 = b2f((u16)(pr >> 16));
      float ss = x0*x0 + x1*x1;
      #pragma unroll
      for (int d = 1; d < 64; d <<= 1) ss += __shfl_xor(ss, d);
      float rinv = rsqrtf(ss * (1.0f / 128.0f) + 1e-6f);
      const float* gg = isq ? gq : gk;
      float2 gv = *(const float2*)(gg + lane * 2);
      float n0 = gv.x * x0 * rinv, n1 = gv.y * x1 * rinv;
      float p0 = __shfl_xor(n0, 32), p1 = __shfl_xor(n1, 32);
      float o0 = n0 * ce0 + sgn * p0 * se0;
      float o1 = n1 * ce1 + sgn * p1 * se1;
      u16* dst;
      if (isq){
        o0 *= QS; o1 *= QS;
        dst = qrot + ((size_t)(b * H_ + head) * T_ + t) * D_;
      } else {
        o0 *= mk; o1 *= mk;
        dst = krot + ((size_t)(b * HKV_ + (head - H_)) * T_ + t) * D_;
      }
      u32 ow = (u32)f2b(o0) | ((u32)f2b(o1) << 16);
      *(u32*)(dst + lane * 2) = ow;
    }
  } else {
    int bid2 = bid - BT_;                      // 0..2047
    int t0 = (bid2 & 31) * 64, d0 = ((bid2 >> 5) & 1) * 64;
    int bh = bid2 >> 6;
    int b = bh >> 3, hk = bh & 7;
    __shared__ __attribute__((aligned(16))) u16 tile[64][68];
    int r = threadIdx.x >> 4, c4 = (threadIdx.x & 15) * 4;
    #pragma unroll
    for (int rr = 0; rr < 4; ++rr){
      int tl = r + rr * 16;
      int t = t0 + tl;
      u16 mz = (u16)(mask[b * T_ + t] ? 0xFFFFu : 0u);
      ushort4 v = *(const ushort4*)(qkv + (size_t)(b * T_ + t) * NQKV_ + HD_ + KVD_ + hk * D_ + d0 + c4);
      tile[tl][c4+0] = (u16)(v.x & mz); tile[tl][c4+1] = (u16)(v.y & mz);
      tile[tl][c4+2] = (u16)(v.z & mz); tile[tl][c4+3] = (u16)(v.w & mz);
    }
    __syncthreads();
    #pragma unroll
    for (int rr = 0; rr < 4; ++rr){
      int dn = r + rr * 16;
      u32 w0 = (u32)tile[c4+0][dn] | ((u32)tile[c4+1][dn] << 16);
      u32 w1 = (u32)tile[c4+2][dn] | ((u32)tile[c4+3][dn] << 16);
      uint2 pk; pk.x = w0; pk.y = w1;
      *(uint2*)(vt + ((size_t)bh * D_ + d0 + dn) * T_ + t0 + c4) = pk;
    }
  }
}

// ---------------------------------------------------------------------------
// Flash attention (causal, GQA 2:1), swapped-QK^T. 8 waves x 16 q-rows
// (QBLK=128) sharing one 64KB double-buffered K/V LDS -> 16 waves/CU.
// global_load_lds staging (4 ops/thread), counted vmcnt(4) + raw s_barrier;
// T2 swizzle via pre-swizzled global source; T13 defer-max THR=8 (log2);
// P-pack via native bf16 casts. Heaviest-first + XCD decode.
__global__ __launch_bounds__(512) void k_attn(const u16* __restrict__ qrot, const u16* __restrict__ krot,
                                              const u16* __restrict__ vt, const int* __restrict__ lens,
                                              u16* __restrict__ ao){
  int fid = blockIdx.x;
  int gs = (fid & 7) * 128 + (fid >> 3);
  int qi = (gs & 15) ^ 15;                 // heaviest (most K-tiles) first
  int q0 = qi * 128;
  int h = (gs >> 4) & 15, b = gs >> 8;
  int hk = h >> 1;
  int tid = threadIdx.x;
  int lane = tid & 63, w = tid >> 6;       // w = 0..7
  int g = lane >> 4, lo = lane & 15;
  int len = lens[b];
  __shared__ __attribute__((aligned(16))) u16 Ks[2][64 * 128];
  __shared__ __attribute__((aligned(16))) u16 Vs[2][128 * 64];
  const u16* qbase = qrot + ((size_t)(b * H_ + h) * T_ + q0 + w * 16 + lo) * D_ + g * 8;
  bf16x8 qf[4];
  #pragma unroll
  for (int kk = 0; kk < 4; ++kk) qf[kk] = *(const bf16x8*)(qbase + kk * 32);
  float m_run = -1e30f, l_run = 0.f;
  f32x4 o[8] = {};
  int qrow = q0 + w * 16 + lo;         // this lane's softmax row
  const u16* kbase = krot + (size_t)(b * HKV_ + hk) * T_ * D_;
  const u16* vbase = vt   + (size_t)(b * HKV_ + hk) * D_ * T_;
  int wbase = tid & 448;               // w*64: wave-uniform granule base
  int lsx = (lo & 7) << 3;             // read-side element XOR
  int srcA = ((lane & 16) * 2 + lo) * 4;  // bpermute byte index
  int srcB = srcA + 64;
  bool hiL = lane >= 32;

  // 4 gload_lds per thread per tile: K 64x16 granules + V 128x8 granules.
  auto STAGE = [&](int j0, int bufi){
    #pragma unroll
    for (int i = 0; i < 2; ++i){
      int gI = i * 512 + tid;
      int row = gI >> 4, grp = gI & 15;
      GLOAD16(kbase + (size_t)(j0 + row) * D_ + ((grp ^ (row & 7)) << 3),
              &Ks[bufi][(i * 512 + wbase) * 8]);
    }
    #pragma unroll
    for (int i = 0; i < 2; ++i){
      int gI = i * 512 + tid;
      int row = gI >> 3, grp = gI & 7;
      GLOAD16(vbase + (size_t)row * T_ + j0 + ((grp ^ (row & 7)) << 3),
              &Vs[bufi][(i * 512 + wbase) * 8]);
    }
  };

  STAGE(0, 0);
  int cur = 0;
  int jend = q0 + 64;                  // last K-tile start for QBLK=128
  for (int j0 = 0; j0 <= jend && j0 < len; j0 += 64){
    int jn = j0 + 64;
    bool hasnext = (jn <= jend && jn < len);
    if (hasnext){
      STAGE(jn, cur ^ 1);
      asm volatile("s_waitcnt vmcnt(4)" ::: "memory");   // tile j0's 4 done
    } else {
      asm volatile("s_waitcnt vmcnt(0)" ::: "memory");
    }
    __builtin_amdgcn_s_barrier();
    __builtin_amdgcn_sched_barrier(0);
    bool wlive = (j0 <= q0 + w * 16 + 15);
    if (wlive){
      // S^T = K * Q^T : st[nf][r] = S[k=j0+nf*16+g*4+r][q=qrow]
      f32x4 st[4] = {};
      __builtin_amdgcn_s_setprio(1);
      #pragma unroll
      for (int kk = 0; kk < 4; ++kk){
        #pragma unroll
        for (int nf = 0; nf < 4; ++nf){
          bf16x8 kf = *(const bf16x8*)&Ks[cur][(nf * 16 + lo) * 128 + ((kk * 32 + g * 8) ^ lsx)];
          st[nf] = MFMA16(kf, qf[kk], st[nf]);
        }
      }
      __builtin_amdgcn_s_setprio(0);
      // mask needed if any lane of this wave has tile-k beyond its row
      bool needmask = (j0 + 63 > q0 + w * 16) || (j0 + 64 > len);
      if (needmask){
        #pragma unroll
        for (int nf = 0; nf < 4; ++nf)
          #pragma unroll
          for (int r = 0; r < 4; ++r){
            int k = j0 + nf * 16 + g * 4 + r;
            if (k > qrow || k >= len) st[nf][r] = -1e30f;
          }
      }
      float mf[4];
      #pragma unroll
      for (int nf = 0; nf < 4; ++nf)
        mf[nf] = fmaxf(fmaxf(st[nf][0], st[nf][1]), fmaxf(st[nf][2], st[nf][3]));
      float mx = fmaxf(fmaxf(mf[0], mf[1]), fmaxf(mf[2], mf[3]));
      mx = fmaxf(mx, __shfl_xor(mx, 16));
      mx = fmaxf(mx, __shfl_xor(mx, 32));
      bool skip = __all(mx <= m_run + 8.0f);   // T13 defer-max, THR=8 (log2)
      float mn = skip ? m_run : fmaxf(m_run, mx);
      float sf[4];
      #pragma unroll
      for (int nf = 0; nf < 4; ++nf){
        #pragma unroll
        for (int r = 0; r < 4; ++r){
          float e = exp2f(st[nf][r] - mn);
          st[nf][r] = e;
        }
        sf[nf] = (st[nf][0] + st[nf][1]) + (st[nf][2] + st[nf][3]);
      }
      float sum = (sf[0] + sf[1]) + (sf[2] + sf[3]);
      sum += __shfl_xor(sum, 16);
      sum += __shfl_xor(sum, 32);
      if (skip){
        l_run += sum;
      } else {
        float alpha = exp2f(m_run - mn);
        l_run = l_run * alpha + sum;
        m_run = mn;
        #pragma unroll
        for (int r = 0; r < 4; ++r){
          float ar = __shfl(alpha, (lane & 48) | ((g * 4 + r) & 15));
          #pragma unroll
          for (int df = 0; df < 8; ++df) o[df][r] *= ar;
        }
      }
      // pack P^T (k-consecutive pairs) -> bf16 u32s via native cvt_pk
      u32 pk[4][2];
      #pragma unroll
      for (int nf = 0; nf < 4; ++nf){
        union { u32 u; __bf16 hh[2]; } c0, c1;
        c0.hh[0] = (__bf16)st[nf][0]; c0.hh[1] = (__bf16)st[nf][1];
        c1.hh[0] = (__bf16)st[nf][2]; c1.hh[1] = (__bf16)st[nf][3];
        pk[nf][0] = c0.u; pk[nf][1] = c1.u;
      }
      // rebuild PV A-frag via bpermute: lane (g,lo) needs P[q=lo][k=kk2*32+8g..+7]
      #pragma unroll
      for (int kk2 = 0; kk2 < 2; ++kk2){
        u32 a0 = (u32)__builtin_amdgcn_ds_bpermute(srcA, (int)pk[2*kk2][0]);
        u32 b0 = (u32)__builtin_amdgcn_ds_bpermute(srcA, (int)pk[2*kk2+1][0]);
        u32 a1 = (u32)__builtin_amdgcn_ds_bpermute(srcA, (int)pk[2*kk2][1]);
        u32 b1 = (u32)__builtin_amdgcn_ds_bpermute(srcA, (int)pk[2*kk2+1][1]);
        u32 a2 = (u32)__builtin_amdgcn_ds_bpermute(srcB, (int)pk[2*kk2][0]);
        u32 b2 = (u32)__builtin_amdgcn_ds_bpermute(srcB, (int)pk[2*kk2+1][0]);
        u32 a3 = (u32)__builtin_amdgcn_ds_bpermute(srcB, (int)pk[2*kk2][1]);
        u32 b3 = (u32)__builtin_amdgcn_ds_bpermute(srcB, (int)pk[2*kk2+1][1]);
        union { u32 u[4]; bf16x8 v; } pf;
        pf.u[0] = hiL ? b0 : a0;
        pf.u[1] = hiL ? b1 : a1;
        pf.u[2] = hiL ? b2 : a2;
        pf.u[3] = hiL ? b3 : a3;
        __builtin_amdgcn_s_setprio(1);
        #pragma unroll
        for (int df = 0; df < 8; ++df){
          bf16x8 vf = *(const bf16x8*)&Vs[cur][(df * 16 + lo) * 64 + ((kk2 * 32 + g * 8) ^ lsx)];
          o[df] = MFMA16(pf.v, vf, o[df]);
        }
        __builtin_amdgcn_s_setprio(0);
      }
    }
    __builtin_amdgcn_s_barrier();     // all waves done reading buf[cur]
    cur ^= 1;
  }
  // epilogue: divide by l (stats live at lane lo = qrow%16), write bf16
  #pragma unroll
  for (int r = 0; r < 4; ++r){
    float lr = __shfl(l_run, (lane & 48) | ((g * 4 + r) & 15));
    float rl = 1.0f / lr;
    int row = q0 + w * 16 + g * 4 + r;
    #pragma unroll
    for (int df = 0; df < 8; ++df){
      float ov = o[df][r] * rl;
      ao[((size_t)(b * T_ + row)) * HD_ + h * D_ + df * 16 + lo] = f2b(ov);
    }
  }
}

// ---------------------------------------------------------------------------
extern "C" void kernel_launch(void* const* d_in, const int* in_sizes, int n_in,
                              void* d_out, int out_size, void* d_ws, size_t ws_size,
                              hipStream_t stream) {
  (void)in_sizes; (void)n_in; (void)out_size; (void)ws_size;
  const float* x    = (const float*)d_in[0];
  const float* cosp = (const float*)d_in[1];
  const float* sinp = (const float*)d_in[2];
  const int*   mask = (const int*)d_in[3];
  const float* Wq   = (const float*)d_in[4];
  const float* bq   = (const float*)d_in[5];
  const float* Wk   = (const float*)d_in[6];
  const float* bk   = (const float*)d_in[7];
  const float* Wv   = (const float*)d_in[8];
  const float* bv   = (const float*)d_in[9];
  const float* gq   = (const float*)d_in[10];
  const float* gk   = (const float*)d_in[11];
  const float* Wo   = (const float*)d_in[12];

  char* ws = (char*)d_ws;
  const size_t MB = 1024 * 1024;
  u16*   XB    = (u16*)(ws);                 // 32MB  x as bf16 [8192][2048]
  u16*   WQKVT = (u16*)(ws + 32  * MB);      // 16MB  [Wq;Wk;Wv]^T bf16 [4096][2048]
  u16*   WOT   = (u16*)(ws + 48  * MB);      //  8MB  Wo^T bf16 [2048][2048]
  u16*   QKV   = (u16*)(ws + 56  * MB);      // 64MB  qkv bf16 [8192][4096]
  u16*   QROT  = (u16*)(ws + 120 * MB);      // 32MB  q rot bf16 [B][H][T][D]
  u16*   KROT  = (u16*)(ws + 152 * MB);      // 16MB  k rot bf16 [B][HKV][T][D]
  u16*   VT    = (u16*)(ws + 168 * MB);      // 16MB  v^T bf16 [B][HKV][D][T]
  u16*   AO    = (u16*)(ws + 184 * MB);      // 32MB  attn out bf16 [8192][2048]
  float* BIAS  = (float*)(ws + 216 * MB);    // 16KB
  int*   LENS  = (int*)(ws + 216 * MB + 65536);

  // merged aux: convx + bias concat + lens (16384 + 16 + 4 blocks)
  k_misc<<<16404, 256, 0, stream>>>(x, XB, bq, bk, bv, BIAS, mask, LENS);
  // merged weight transposes (z: Wq, Wo, Wk, Wv)
  k_wtrans<<<dim3(32, 32, 4), 256, 0, stream>>>(Wq, Wk, Wv, Wo, WQKVT, WOT);

  // qkv = x @ [Wq|Wk|Wv] + bias (bf16 out): 128x256 tiles -> 64x16 = 1024 blocks
  k_gemm<false><<<1024, 512, 0, stream>>>(XB, WQKVT, BIAS, QKV, BT_, NQKV_, C_, 16);
  // merged: RMSNorm+mRoPE (blocks 0..8191) + masked V transpose (8192..10239)
  k_post<<<BT_ + 2048, 256, 0, stream>>>(QKV, cosp, sinp, mask, gq, gk, QROT, KROT, VT);
  // causal GQA flash attention (8-wave blocks, QBLK=128, heaviest-first, XCD)
  k_attn<<<1024, 512, 0, stream>>>(QROT, KROT, VT, LENS, AO);
  // out = AO @ Wo (fp32 out): 128x256 tiles -> 64x8 = 512 blocks
  k_gemm<true><<<512, 512, 0, stream>>>(AO, WOT, nullptr, d_out, BT_, C_, HD_, 8);
}

// Round 17
// 463.974 us; speedup vs baseline: 1.0333x; 1.0333x over previous
//
#include <hip/hip_runtime.h>
#include <stdint.h>

// Problem constants
#define B_    4
#define T_    2048
#define C_    2048
#define H_    16
#define HKV_  8
#define D_    128
#define HD_   2048      // H_*D_
#define KVD_  1024      // HKV_*D_
#define NQKV_ 4096      // HD_+2*KVD_
#define BT_   8192      // B_*T_

typedef __bf16 bf16x8 __attribute__((ext_vector_type(8)));
typedef float  f32x4  __attribute__((ext_vector_type(4)));
typedef unsigned short u16;
typedef unsigned int   u32;

__device__ __forceinline__ u16 f2b(float f){
  union { float f; u32 u; } v; v.f = f;
  u32 r = v.u + 0x7FFFu + ((v.u >> 16) & 1u);   // RNE
  return (u16)(r >> 16);
}
__device__ __forceinline__ float b2f(u16 h){
  union { u32 u; float f; } v; v.u = ((u32)h) << 16;
  return v.f;
}

#define GLOAD16(src, dst) __builtin_amdgcn_global_load_lds( \
    (const __attribute__((address_space(1))) u32*)(src), \
    (__attribute__((address_space(3))) u32*)(dst), 16, 0, 0)

#define MFMA16(a,b,c) __builtin_amdgcn_mfma_f32_16x16x32_bf16((a), (b), (c), 0, 0, 0)

// ---------------------------------------------------------------------------
// merged: fp32->bf16 convert (x) + bias concat + per-batch lens
__global__ __launch_bounds__(256) void k_misc(const float* __restrict__ x, u16* __restrict__ xb,
                                              const float* __restrict__ bq, const float* __restrict__ bk,
                                              const float* __restrict__ bv, float* __restrict__ bias,
                                              const int* __restrict__ mask, int* __restrict__ lens){
  int bid = blockIdx.x;
  if (bid < 16384){
    size_t i = ((size_t)bid * 256 + threadIdx.x) * 4;
    float4 v = *(const float4*)(x + i);
    u32 w0 = (u32)f2b(v.x) | ((u32)f2b(v.y) << 16);
    u32 w1 = (u32)f2b(v.z) | ((u32)f2b(v.w) << 16);
    uint2 pk; pk.x = w0; pk.y = w1;
    *(uint2*)(xb + i) = pk;
  } else if (bid < 16400){
    int i = (bid - 16384) * 256 + threadIdx.x;
    if (i < NQKV_)
      bias[i] = (i < HD_) ? bq[i] : (i < HD_ + KVD_ ? bk[i - HD_] : bv[i - HD_ - KVD_]);
  } else {
    int b = bid - 16400;
    int s = 0;
    for (int t = threadIdx.x; t < T_; t += 256) s += mask[b * T_ + t];
    #pragma unroll
    for (int d = 1; d < 64; d <<= 1) s += __shfl_xor(s, d);
    __shared__ int acc[4];
    if ((threadIdx.x & 63) == 0) acc[threadIdx.x >> 6] = s;
    __syncthreads();
    if (threadIdx.x == 0) lens[b] = acc[0] + acc[1] + acc[2] + acc[3];
  }
}

// transpose + convert all four weights in one launch.
__global__ __launch_bounds__(256) void k_wtrans(const float* __restrict__ Wq, const float* __restrict__ Wk,
                                                const float* __restrict__ Wv, const float* __restrict__ Wo,
                                                u16* __restrict__ WQKVT, u16* __restrict__ WOT){
  int z = blockIdx.z;
  const float* src; u16* dst; int N;
  if (z == 0){ src = Wq; dst = WQKVT;                          N = 2048; }
  else if (z == 1){ src = Wo; dst = WOT;                       N = 2048; }
  else if (z == 2){ src = Wk; dst = WQKVT + (size_t)HD_ * C_;  N = 1024; }
  else { src = Wv; dst = WQKVT + (size_t)(HD_ + KVD_) * C_;    N = 1024; }
  if (blockIdx.x * 64 >= N) return;
  const int K = 2048;
  __shared__ __attribute__((aligned(16))) u16 tile[64][68];
  int n0 = blockIdx.x * 64, k0 = blockIdx.y * 64;
  int r = threadIdx.x >> 4, c4 = (threadIdx.x & 15) * 4;
  #pragma unroll
  for (int rr = 0; rr < 4; ++rr){
    int kl = r + rr * 16;
    float4 v = *(const float4*)(src + (size_t)(k0 + kl) * N + n0 + c4);
    tile[kl][c4+0] = f2b(v.x); tile[kl][c4+1] = f2b(v.y);
    tile[kl][c4+2] = f2b(v.z); tile[kl][c4+3] = f2b(v.w);
  }
  __syncthreads();
  #pragma unroll
  for (int rr = 0; rr < 4; ++rr){
    int nl = r + rr * 16;
    u32 w0 = (u32)tile[c4+0][nl] | ((u32)tile[c4+1][nl] << 16);
    u32 w1 = (u32)tile[c4+2][nl] | ((u32)tile[c4+3][nl] << 16);
    uint2 pk; pk.x = w0; pk.y = w1;
    *(uint2*)(dst + (size_t)(n0 + nl) * K + k0 + c4) = pk;
  }
}

// ---------------------------------------------------------------------------
// R17: true 8-phase QKV GEMM (third attempt, both prior failure mechanisms
// fixed). 256x256, BK=64, 8 waves (2M x 4N), 128KB dbuf, K-split halves
// h={A-k0,B-k0,A-k1,B-k1} (each 256x32). Per tile: 4 phases x ~16 MFMA.
//   R9 fix: every half has 3-4 phases of issue lead (vmcnt(6) steady).
//   R12 fix: phases 1,3 MFMA on PRE-READ regs (reads hoisted before the
//   previous barrier -> hidden under MFMA drain + barrier skew).
__global__ __launch_bounds__(512) void k_gemm8(const u16* __restrict__ A, const u16* __restrict__ BT,
                                               const float* __restrict__ bias, u16* __restrict__ Cout,
                                               int M, int N, int K, int nbx){
  __shared__ __attribute__((aligned(16))) u16 As[2][2][8192];   // [buf][khalf][256*32]
  __shared__ __attribute__((aligned(16))) u16 Bs[2][2][8192];
  int nwg = gridDim.x;
  int fid = blockIdx.x;
  int gs = (fid & 7) * (nwg >> 3) + (fid >> 3);
  int bx = gs % nbx, by = gs / nbx;
  int m0 = by * 256, n0 = bx * 256;
  int tid = threadIdx.x;
  int lane = tid & 63, w = tid >> 6;
  int wm = w >> 2, wn = w & 3;
  int g = lane >> 4, lo = lane & 15;
  int wgb = tid & 448;
  f32x4 acc[8][4] = {};

  auto STAGE_HALF = [&](const u16* __restrict__ src, int kbase, u16* lds){
    #pragma unroll
    for (int i = 0; i < 2; ++i){
      int gI = i * 512 + tid;
      int row = gI >> 2, gsl = gI & 3;
      GLOAD16(src + (size_t)row * K + kbase + ((gsl ^ ((row >> 1) & 3)) << 3),
              &lds[(i * 512 + wgb) * 8]);
    }
  };
  auto ISSUE = [&](int kt, int h, int b){
    int kbase = kt * 64 + (h >> 1) * 32;
    if ((h & 1) == 0) STAGE_HALF(A  + (size_t)m0 * K, kbase, &As[b][h >> 1][0]);
    else              STAGE_HALF(BT + (size_t)n0 * K, kbase, &Bs[b][h >> 1][0]);
  };
  auto RD_B = [&](int cur, int kh, int nf) -> bf16x8 {
    int brow = wn * 64 + nf * 16 + lo;
    return *(const bf16x8*)&Bs[cur][kh][brow * 32 + ((g ^ ((brow >> 1) & 3)) << 3)];
  };
  auto RD_A = [&](int cur, int kh, int i, int mh) -> bf16x8 {
    int arow = wm * 128 + mh * 64 + i * 16 + lo;
    return *(const bf16x8*)&As[cur][kh][arow * 32 + ((g ^ ((arow >> 1) & 3)) << 3)];
  };

  int nk = K >> 6;
  ISSUE(0, 0, 0); ISSUE(0, 1, 0); ISSUE(0, 2, 0); ISSUE(0, 3, 0);
  for (int t = 0; t < nk; ++t){
    int cur = t & 1, nxt = cur ^ 1;
    bool pf = (t + 1 < nk);
    bf16x8 bfr[4], af[4], afn[4];
    // ---- phase 0: k0, M-lo ----
    if (pf){ ISSUE(t + 1, 0, nxt); asm volatile("s_waitcnt vmcnt(6)" ::: "memory"); }
    else   {                       asm volatile("s_waitcnt vmcnt(4)" ::: "memory"); }
    __builtin_amdgcn_s_barrier();
    __builtin_amdgcn_sched_barrier(0);
    #pragma unroll
    for (int nf = 0; nf < 4; ++nf) bfr[nf] = RD_B(cur, 0, nf);
    #pragma unroll
    for (int i = 0; i < 4; ++i)    af[i]  = RD_A(cur, 0, i, 0);
    __builtin_amdgcn_s_setprio(1);
    #pragma unroll
    for (int i = 0; i < 4; ++i)
      #pragma unroll
      for (int nf = 0; nf < 4; ++nf)
        acc[i][nf] = MFMA16(af[i], bfr[nf], acc[i][nf]);
    __builtin_amdgcn_s_setprio(0);
    if (pf) ISSUE(t + 1, 1, nxt);
    #pragma unroll
    for (int i = 0; i < 4; ++i)    afn[i] = RD_A(cur, 0, i, 1);   // pre-read M-hi
    __builtin_amdgcn_s_barrier();
    // ---- phase 1: k0, M-hi (register-only critical path) ----
    __builtin_amdgcn_s_setprio(1);
    #pragma unroll
    for (int i = 0; i < 4; ++i)
      #pragma unroll
      for (int nf = 0; nf < 4; ++nf)
        acc[4 + i][nf] = MFMA16(afn[i], bfr[nf], acc[4 + i][nf]);
    __builtin_amdgcn_s_setprio(0);
    if (pf){ ISSUE(t + 1, 2, nxt); asm volatile("s_waitcnt vmcnt(6)" ::: "memory"); }
    else   {                       asm volatile("s_waitcnt vmcnt(0)" ::: "memory"); }
    __builtin_amdgcn_s_barrier();
    __builtin_amdgcn_sched_barrier(0);
    // ---- phase 2: k1, M-lo ----
    #pragma unroll
    for (int nf = 0; nf < 4; ++nf) bfr[nf] = RD_B(cur, 1, nf);
    #pragma unroll
    for (int i = 0; i < 4; ++i)    af[i]  = RD_A(cur, 1, i, 0);
    __builtin_amdgcn_s_setprio(1);
    #pragma unroll
    for (int i = 0; i < 4; ++i)
      #pragma unroll
      for (int nf = 0; nf < 4; ++nf)
        acc[i][nf] = MFMA16(af[i], bfr[nf], acc[i][nf]);
    __builtin_amdgcn_s_setprio(0);
    if (pf) ISSUE(t + 1, 3, nxt);
    #pragma unroll
    for (int i = 0; i < 4; ++i)    afn[i] = RD_A(cur, 1, i, 1);   // pre-read M-hi
    __builtin_amdgcn_s_barrier();
    // ---- phase 3: k1, M-hi (register-only; tile-end barrier folded into
    // next tile's phase-0 barrier — the only inter-region write targets
    // disjoint LDS halves, verified hazard analysis) ----
    __builtin_amdgcn_s_setprio(1);
    #pragma unroll
    for (int i = 0; i < 4; ++i)
      #pragma unroll
      for (int nf = 0; nf < 4; ++nf)
        acc[4 + i][nf] = MFMA16(afn[i], bfr[nf], acc[4 + i][nf]);
    __builtin_amdgcn_s_setprio(0);
  }
  #pragma unroll
  for (int mr = 0; mr < 8; ++mr){
    #pragma unroll
    for (int nr = 0; nr < 4; ++nr){
      #pragma unroll
      for (int r = 0; r < 4; ++r){
        int row = m0 + wm * 128 + mr * 16 + g * 4 + r;
        int col = n0 + wn * 64 + nr * 16 + lo;
        Cout[(size_t)row * N + col] = f2b(acc[mr][nr][r] + bias[col]);
      }
    }
  }
}

// ---------------------------------------------------------------------------
// bf16 GEMM (verified 2-phase template), used for the out-projection.
// 128x256 tile, BK=32, 8 waves, 48KB dbuf, vmcnt(3), 2 barriers/tile.
template<bool OUTF32>
__global__ __launch_bounds__(512, 4) void k_gemm(const u16* __restrict__ A, const u16* __restrict__ BT,
                                                 const float* __restrict__ bias, void* __restrict__ Cout,
                                                 int M, int N, int K, int nbx){
  __shared__ __attribute__((aligned(16))) u16 As[2][128 * 32];   // 16 KB
  __shared__ __attribute__((aligned(16))) u16 Bs[2][256 * 32];   // 32 KB
  int nwg = gridDim.x;
  int fid = blockIdx.x;
  int gs = (fid & 7) * (nwg >> 3) + (fid >> 3);   // XCD-chunked decode
  int bx = gs % nbx, by = gs / nbx;
  int m0 = by * 128, n0 = bx * 256;
  int tid = threadIdx.x;
  int lane = tid & 63, w = tid >> 6;              // 8 waves
  int wm = w >> 2, wn = w & 3;                    // 2 x 4 wave grid
  int g = lane >> 4, lo = lane & 15;
  f32x4 acc[4][4] = {};

  auto STAGE_TILE = [&](int k0, int bufi){
    {
      int row = tid >> 2, gr = tid & 3;
      GLOAD16(A + (size_t)(m0 + row) * K + k0 + ((gr ^ ((row >> 1) & 3)) << 3),
              &As[bufi][(tid & 448) * 8]);
    }
    #pragma unroll
    for (int i = 0; i < 2; ++i){
      int gI = i * 512 + tid;
      int row = gI >> 2, gr = gI & 3;
      GLOAD16(BT + (size_t)(n0 + row) * K + k0 + ((gr ^ ((row >> 1) & 3)) << 3),
              &Bs[bufi][(i * 512 + (tid & 448)) * 8]);
    }
  };

  int nk = K >> 5;                       // BK = 32
  STAGE_TILE(0, 0);
  for (int t = 0; t < nk; ++t){
    int cur = t & 1, nxt = cur ^ 1;
    bool pf = (t + 1 < nk);
    if (pf){
      STAGE_TILE((t + 1) * 32, nxt);
      asm volatile("s_waitcnt vmcnt(3)" ::: "memory");   // tile t's 3 landed
    } else {
      asm volatile("s_waitcnt vmcnt(0)" ::: "memory");
    }
    __builtin_amdgcn_s_barrier();
    __builtin_amdgcn_sched_barrier(0);
    bf16x8 bfr[4], af[4];
    #pragma unroll
    for (int nr = 0; nr < 4; ++nr){
      int brow = wn * 64 + nr * 16 + lo;
      bfr[nr] = *(const bf16x8*)&Bs[cur][brow * 32 + ((g ^ ((brow >> 1) & 3)) << 3)];
    }
    #pragma unroll
    for (int mr = 0; mr < 4; ++mr){
      int arow = wm * 64 + mr * 16 + lo;
      af[mr] = *(const bf16x8*)&As[cur][arow * 32 + ((g ^ ((arow >> 1) & 3)) << 3)];
    }
    __builtin_amdgcn_s_setprio(1);
    #pragma unroll
    for (int mr = 0; mr < 4; ++mr)
      #pragma unroll
      for (int nr = 0; nr < 4; ++nr)
        acc[mr][nr] = MFMA16(af[mr], bfr[nr], acc[mr][nr]);
    __builtin_amdgcn_s_setprio(0);
    __builtin_amdgcn_s_barrier();
  }
  #pragma unroll
  for (int mr = 0; mr < 4; ++mr){
    #pragma unroll
    for (int nr = 0; nr < 4; ++nr){
      #pragma unroll
      for (int r = 0; r < 4; ++r){
        int row = m0 + wm * 64 + mr * 16 + g * 4 + r;
        int col = n0 + wn * 64 + nr * 16 + lo;
        float v = acc[mr][nr][r] + (bias ? bias[col] : 0.0f);
        if (OUTF32) ((float*)Cout)[(size_t)row * N + col] = v;
        else        ((u16*)Cout)[(size_t)row * N + col] = f2b(v);
      }
    }
  }
}

// ---------------------------------------------------------------------------
// merged post-QKV pass: blocks 0..8191 = RMSNorm+mRoPE (per token);
// blocks 8192..10239 = masked V transpose. Disjoint outputs, both read QKV.
__global__ __launch_bounds__(256) void k_post(const u16* __restrict__ qkv,
    const float* __restrict__ cosp, const float* __restrict__ sinp,
    const int* __restrict__ mask, const float* __restrict__ gq, const float* __restrict__ gk,
    u16* __restrict__ qrot, u16* __restrict__ krot, u16* __restrict__ vt){
  int bid = blockIdx.x;
  if (bid < BT_){
    const float QS = 0.08838834764831845f * 1.4426950408889634f;  // scale * log2e
    int tok = bid;
    int b = tok >> 11, t = tok & (T_ - 1);
    int lane = threadIdx.x & 63, w = threadIdx.x >> 6;
    int dl = (lane & 31) * 2;                 // index into the 64-entry half table
    int a0 = dl < 24 ? 0 : (dl < 44 ? 1 : 2);
    int a1 = (dl + 1) < 24 ? 0 : ((dl + 1) < 44 ? 1 : 2);
    size_t cb = ((size_t)b * T_ + t) * 64;
    const size_t AX = (size_t)B_ * T_ * 64;
    float ce0 = cosp[(size_t)a0 * AX + cb + dl],     se0 = sinp[(size_t)a0 * AX + cb + dl];
    float ce1 = cosp[(size_t)a1 * AX + cb + dl + 1], se1 = sinp[(size_t)a1 * AX + cb + dl + 1];
    float sgn = (lane < 32) ? -1.f : 1.f;
    float mk = (float)mask[b * T_ + t];
    const u16* base = qkv + (size_t)tok * NQKV_;
    for (int head = w; head < H_ + HKV_; head += 4){
      bool isq = head < H_;
      int off = isq ? head * D_ : HD_ + (head - H_) * D_;
      u32 pr = *(const u32*)(base + off + lane * 2);
      float x0 = b2f((u16)(pr & 0xFFFF)), x1 = b2f((u16)(pr >> 16));
      float ss = x0*x0 + x1*x1;
      #pragma unroll
      for (int d = 1; d < 64; d <<= 1) ss += __shfl_xor(ss, d);
      float rinv = rsqrtf(ss * (1.0f / 128.0f) + 1e-6f);
      const float* gg = isq ? gq : gk;
      float2 gv = *(const float2*)(gg + lane * 2);
      float n0 = gv.x * x0 * rinv, n1 = gv.y * x1 * rinv;
      float p0 = __shfl_xor(n0, 32), p1 = __shfl_xor(n1, 32);
      float o0 = n0 * ce0 + sgn * p0 * se0;
      float o1 = n1 * ce1 + sgn * p1 * se1;
      u16* dst;
      if (isq){
        o0 *= QS; o1 *= QS;
        dst = qrot + ((size_t)(b * H_ + head) * T_ + t) * D_;
      } else {
        o0 *= mk; o1 *= mk;
        dst = krot + ((size_t)(b * HKV_ + (head - H_)) * T_ + t) * D_;
      }
      u32 ow = (u32)f2b(o0) | ((u32)f2b(o1) << 16);
      *(u32*)(dst + lane * 2) = ow;
    }
  } else {
    int bid2 = bid - BT_;                      // 0..2047
    int t0 = (bid2 & 31) * 64, d0 = ((bid2 >> 5) & 1) * 64;
    int bh = bid2 >> 6;
    int b = bh >> 3, hk = bh & 7;
    __shared__ __attribute__((aligned(16))) u16 tile[64][68];
    int r = threadIdx.x >> 4, c4 = (threadIdx.x & 15) * 4;
    #pragma unroll
    for (int rr = 0; rr < 4; ++rr){
      int tl = r + rr * 16;
      int t = t0 + tl;
      u16 mz = (u16)(mask[b * T_ + t] ? 0xFFFFu : 0u);
      ushort4 v = *(const ushort4*)(qkv + (size_t)(b * T_ + t) * NQKV_ + HD_ + KVD_ + hk * D_ + d0 + c4);
      tile[tl][c4+0] = (u16)(v.x & mz); tile[tl][c4+1] = (u16)(v.y & mz);
      tile[tl][c4+2] = (u16)(v.z & mz); tile[tl][c4+3] = (u16)(v.w & mz);
    }
    __syncthreads();
    #pragma unroll
    for (int rr = 0; rr < 4; ++rr){
      int dn = r + rr * 16;
      u32 w0 = (u32)tile[c4+0][dn] | ((u32)tile[c4+1][dn] << 16);
      u32 w1 = (u32)tile[c4+2][dn] | ((u32)tile[c4+3][dn] << 16);
      uint2 pk; pk.x = w0; pk.y = w1;
      *(uint2*)(vt + ((size_t)bh * D_ + d0 + dn) * T_ + t0 + c4) = pk;
    }
  }
}

// ---------------------------------------------------------------------------
// Flash attention (causal, GQA 2:1), swapped-QK^T. 8 waves x 16 q-rows
// (QBLK=128) sharing one 64KB double-buffered K/V LDS -> 16 waves/CU.
// global_load_lds staging (4 ops/thread), counted vmcnt(4) + raw s_barrier;
// T2 swizzle via pre-swizzled global source; T13 defer-max THR=8 (log2);
// P-pack via native bf16 casts. Heaviest-first + XCD decode.
__global__ __launch_bounds__(512) void k_attn(const u16* __restrict__ qrot, const u16* __restrict__ krot,
                                              const u16* __restrict__ vt, const int* __restrict__ lens,
                                              u16* __restrict__ ao){
  int fid = blockIdx.x;
  int gs = (fid & 7) * 128 + (fid >> 3);
  int qi = (gs & 15) ^ 15;                 // heaviest (most K-tiles) first
  int q0 = qi * 128;
  int h = (gs >> 4) & 15, b = gs >> 8;
  int hk = h >> 1;
  int tid = threadIdx.x;
  int lane = tid & 63, w = tid >> 6;       // w = 0..7
  int g = lane >> 4, lo = lane & 15;
  int len = lens[b];
  __shared__ __attribute__((aligned(16))) u16 Ks[2][64 * 128];
  __shared__ __attribute__((aligned(16))) u16 Vs[2][128 * 64];
  const u16* qbase = qrot + ((size_t)(b * H_ + h) * T_ + q0 + w * 16 + lo) * D_ + g * 8;
  bf16x8 qf[4];
  #pragma unroll
  for (int kk = 0; kk < 4; ++kk) qf[kk] = *(const bf16x8*)(qbase + kk * 32);
  float m_run = -1e30f, l_run = 0.f;
  f32x4 o[8] = {};
  int qrow = q0 + w * 16 + lo;         // this lane's softmax row
  const u16* kbase = krot + (size_t)(b * HKV_ + hk) * T_ * D_;
  const u16* vbase = vt   + (size_t)(b * HKV_ + hk) * D_ * T_;
  int wbase = tid & 448;               // w*64: wave-uniform granule base
  int lsx = (lo & 7) << 3;             // read-side element XOR
  int srcA = ((lane & 16) * 2 + lo) * 4;  // bpermute byte index
  int srcB = srcA + 64;
  bool hiL = lane >= 32;

  // 4 gload_lds per thread per tile: K 64x16 granules + V 128x8 granules.
  auto STAGE = [&](int j0, int bufi){
    #pragma unroll
    for (int i = 0; i < 2; ++i){
      int gI = i * 512 + tid;
      int row = gI >> 4, grp = gI & 15;
      GLOAD16(kbase + (size_t)(j0 + row) * D_ + ((grp ^ (row & 7)) << 3),
              &Ks[bufi][(i * 512 + wbase) * 8]);
    }
    #pragma unroll
    for (int i = 0; i < 2; ++i){
      int gI = i * 512 + tid;
      int row = gI >> 3, grp = gI & 7;
      GLOAD16(vbase + (size_t)row * T_ + j0 + ((grp ^ (row & 7)) << 3),
              &Vs[bufi][(i * 512 + wbase) * 8]);
    }
  };

  STAGE(0, 0);
  int cur = 0;
  int jend = q0 + 64;                  // last K-tile start for QBLK=128
  for (int j0 = 0; j0 <= jend && j0 < len; j0 += 64){
    int jn = j0 + 64;
    bool hasnext = (jn <= jend && jn < len);
    if (hasnext){
      STAGE(jn, cur ^ 1);
      asm volatile("s_waitcnt vmcnt(4)" ::: "memory");   // tile j0's 4 done
    } else {
      asm volatile("s_waitcnt vmcnt(0)" ::: "memory");
    }
    __builtin_amdgcn_s_barrier();
    __builtin_amdgcn_sched_barrier(0);
    bool wlive = (j0 <= q0 + w * 16 + 15);
    if (wlive){
      // S^T = K * Q^T : st[nf][r] = S[k=j0+nf*16+g*4+r][q=qrow]
      f32x4 st[4] = {};
      __builtin_amdgcn_s_setprio(1);
      #pragma unroll
      for (int kk = 0; kk < 4; ++kk){
        #pragma unroll
        for (int nf = 0; nf < 4; ++nf){
          bf16x8 kf = *(const bf16x8*)&Ks[cur][(nf * 16 + lo) * 128 + ((kk * 32 + g * 8) ^ lsx)];
          st[nf] = MFMA16(kf, qf[kk], st[nf]);
        }
      }
      __builtin_amdgcn_s_setprio(0);
      // mask needed if any lane of this wave has tile-k beyond its row
      bool needmask = (j0 + 63 > q0 + w * 16) || (j0 + 64 > len);
      if (needmask){
        #pragma unroll
        for (int nf = 0; nf < 4; ++nf)
          #pragma unroll
          for (int r = 0; r < 4; ++r){
            int k = j0 + nf * 16 + g * 4 + r;
            if (k > qrow || k >= len) st[nf][r] = -1e30f;
          }
      }
      float mf[4];
      #pragma unroll
      for (int nf = 0; nf < 4; ++nf)
        mf[nf] = fmaxf(fmaxf(st[nf][0], st[nf][1]), fmaxf(st[nf][2], st[nf][3]));
      float mx = fmaxf(fmaxf(mf[0], mf[1]), fmaxf(mf[2], mf[3]));
      mx = fmaxf(mx, __shfl_xor(mx, 16));
      mx = fmaxf(mx, __shfl_xor(mx, 32));
      bool skip = __all(mx <= m_run + 8.0f);   // T13 defer-max, THR=8 (log2)
      float mn = skip ? m_run : fmaxf(m_run, mx);
      float sf[4];
      #pragma unroll
      for (int nf = 0; nf < 4; ++nf){
        #pragma unroll
        for (int r = 0; r < 4; ++r){
          float e = exp2f(st[nf][r] - mn);
          st[nf][r] = e;
        }
        sf[nf] = (st[nf][0] + st[nf][1]) + (st[nf][2] + st[nf][3]);
      }
      float sum = (sf[0] + sf[1]) + (sf[2] + sf[3]);
      sum += __shfl_xor(sum, 16);
      sum += __shfl_xor(sum, 32);
      if (skip){
        l_run += sum;
      } else {
        float alpha = exp2f(m_run - mn);
        l_run = l_run * alpha + sum;
        m_run = mn;
        #pragma unroll
        for (int r = 0; r < 4; ++r){
          float ar = __shfl(alpha, (lane & 48) | ((g * 4 + r) & 15));
          #pragma unroll
          for (int df = 0; df < 8; ++df) o[df][r] *= ar;
        }
      }
      // pack P^T (k-consecutive pairs) -> bf16 u32s via native cvt_pk
      u32 pk[4][2];
      #pragma unroll
      for (int nf = 0; nf < 4; ++nf){
        union { u32 u; __bf16 hh[2]; } c0, c1;
        c0.hh[0] = (__bf16)st[nf][0]; c0.hh[1] = (__bf16)st[nf][1];
        c1.hh[0] = (__bf16)st[nf][2]; c1.hh[1] = (__bf16)st[nf][3];
        pk[nf][0] = c0.u; pk[nf][1] = c1.u;
      }
      // rebuild PV A-frag via bpermute: lane (g,lo) needs P[q=lo][k=kk2*32+8g..+7]
      #pragma unroll
      for (int kk2 = 0; kk2 < 2; ++kk2){
        u32 a0 = (u32)__builtin_amdgcn_ds_bpermute(srcA, (int)pk[2*kk2][0]);
        u32 b0 = (u32)__builtin_amdgcn_ds_bpermute(srcA, (int)pk[2*kk2+1][0]);
        u32 a1 = (u32)__builtin_amdgcn_ds_bpermute(srcA, (int)pk[2*kk2][1]);
        u32 b1 = (u32)__builtin_amdgcn_ds_bpermute(srcA, (int)pk[2*kk2+1][1]);
        u32 a2 = (u32)__builtin_amdgcn_ds_bpermute(srcB, (int)pk[2*kk2][0]);
        u32 b2 = (u32)__builtin_amdgcn_ds_bpermute(srcB, (int)pk[2*kk2+1][0]);
        u32 a3 = (u32)__builtin_amdgcn_ds_bpermute(srcB, (int)pk[2*kk2][1]);
        u32 b3 = (u32)__builtin_amdgcn_ds_bpermute(srcB, (int)pk[2*kk2+1][1]);
        union { u32 u[4]; bf16x8 v; } pf;
        pf.u[0] = hiL ? b0 : a0;
        pf.u[1] = hiL ? b1 : a1;
        pf.u[2] = hiL ? b2 : a2;
        pf.u[3] = hiL ? b3 : a3;
        __builtin_amdgcn_s_setprio(1);
        #pragma unroll
        for (int df = 0; df < 8; ++df){
          bf16x8 vf = *(const bf16x8*)&Vs[cur][(df * 16 + lo) * 64 + ((kk2 * 32 + g * 8) ^ lsx)];
          o[df] = MFMA16(pf.v, vf, o[df]);
        }
        __builtin_amdgcn_s_setprio(0);
      }
    }
    __builtin_amdgcn_s_barrier();     // all waves done reading buf[cur]
    cur ^= 1;
  }
  // epilogue: divide by l (stats live at lane lo = qrow%16), write bf16
  #pragma unroll
  for (int r = 0; r < 4; ++r){
    float lr = __shfl(l_run, (lane & 48) | ((g * 4 + r) & 15));
    float rl = 1.0f / lr;
    int row = q0 + w * 16 + g * 4 + r;
    #pragma unroll
    for (int df = 0; df < 8; ++df){
      float ov = o[df][r] * rl;
      ao[((size_t)(b * T_ + row)) * HD_ + h * D_ + df * 16 + lo] = f2b(ov);
    }
  }
}

// ---------------------------------------------------------------------------
extern "C" void kernel_launch(void* const* d_in, const int* in_sizes, int n_in,
                              void* d_out, int out_size, void* d_ws, size_t ws_size,
                              hipStream_t stream) {
  (void)in_sizes; (void)n_in; (void)out_size; (void)ws_size;
  const float* x    = (const float*)d_in[0];
  const float* cosp = (const float*)d_in[1];
  const float* sinp = (const float*)d_in[2];
  const int*   mask = (const int*)d_in[3];
  const float* Wq   = (const float*)d_in[4];
  const float* bq   = (const float*)d_in[5];
  const float* Wk   = (const float*)d_in[6];
  const float* bk   = (const float*)d_in[7];
  const float* Wv   = (const float*)d_in[8];
  const float* bv   = (const float*)d_in[9];
  const float* gq   = (const float*)d_in[10];
  const float* gk   = (const float*)d_in[11];
  const float* Wo   = (const float*)d_in[12];

  char* ws = (char*)d_ws;
  const size_t MB = 1024 * 1024;
  u16*   XB    = (u16*)(ws);                 // 32MB  x as bf16 [8192][2048]
  u16*   WQKVT = (u16*)(ws + 32  * MB);      // 16MB  [Wq;Wk;Wv]^T bf16 [4096][2048]
  u16*   WOT   = (u16*)(ws + 48  * MB);      //  8MB  Wo^T bf16 [2048][2048]
  u16*   QKV   = (u16*)(ws + 56  * MB);      // 64MB  qkv bf16 [8192][4096]
  u16*   QROT  = (u16*)(ws + 120 * MB);      // 32MB  q rot bf16 [B][H][T][D]
  u16*   KROT  = (u16*)(ws + 152 * MB);      // 16MB  k rot bf16 [B][HKV][T][D]
  u16*   VT    = (u16*)(ws + 168 * MB);      // 16MB  v^T bf16 [B][HKV][D][T]
  u16*   AO    = (u16*)(ws + 184 * MB);      // 32MB  attn out bf16 [8192][2048]
  float* BIAS  = (float*)(ws + 216 * MB);    // 16KB
  int*   LENS  = (int*)(ws + 216 * MB + 65536);

  // merged aux: convx + bias concat + lens (16384 + 16 + 4 blocks)
  k_misc<<<16404, 256, 0, stream>>>(x, XB, bq, bk, bv, BIAS, mask, LENS);
  // merged weight transposes (z: Wq, Wo, Wk, Wv)
  k_wtrans<<<dim3(32, 32, 4), 256, 0, stream>>>(Wq, Wk, Wv, Wo, WQKVT, WOT);

  // qkv = x @ [Wq|Wk|Wv] + bias (bf16 out): 8-phase 256x256 -> 512 blocks
  k_gemm8<<<512, 512, 0, stream>>>(XB, WQKVT, BIAS, QKV, BT_, NQKV_, C_, 16);
  // merged: RMSNorm+mRoPE (blocks 0..8191) + masked V transpose (8192..10239)
  k_post<<<BT_ + 2048, 256, 0, stream>>>(QKV, cosp, sinp, mask, gq, gk, QROT, KROT, VT);
  // causal GQA flash attention (8-wave blocks, QBLK=128, heaviest-first, XCD)
  k_attn<<<1024, 512, 0, stream>>>(QROT, KROT, VT, LENS, AO);
  // out = AO @ Wo (fp32 out): 2-phase 128x256 -> 512 blocks
  k_gemm<true><<<512, 512, 0, stream>>>(AO, WOT, nullptr, d_out, BT_, C_, HD_, 8);
}